// Round 4
// baseline (250.166 us; speedup 1.0000x reference)
//
#include <hip/hip_runtime.h>
#include <math.h>

#define NB 131072
#define NSTEPS 30

typedef float  float4v __attribute__((ext_vector_type(4)));
typedef short  short4v __attribute__((ext_vector_type(4)));

#define MFMA16 __builtin_amdgcn_mfma_f32_16x16x16bf16_1k

static __device__ __forceinline__ unsigned fb(float f) {
    union { float f; unsigned u; } c; c.f = f; return c.u;
}
static __device__ __forceinline__ float fu(unsigned u) {
    union { unsigned u; float f; } c; c.u = u; return c.f;
}

struct bfpair { short4v hi, lo; };

// Truncation split, pure C++ (no inline asm), packed with v_perm:
//   hi = trunc_bf16(v); lo_exact = v - hi (EXACT in f32); lo = trunc_bf16(lo_exact)
// v = hi + lo + err, |err| <= 2^-16 |v|.   12 VALU ops per 4 values.
static __device__ __forceinline__ bfpair split4(float4v v) {
    unsigned u0 = fb(v[0]), u1 = fb(v[1]), u2 = fb(v[2]), u3 = fb(v[3]);
    float l0 = v[0] - fu(u0 & 0xffff0000u);
    float l1 = v[1] - fu(u1 & 0xffff0000u);
    float l2 = v[2] - fu(u2 & 0xffff0000u);
    float l3 = v[3] - fu(u3 & 0xffff0000u);
    union { unsigned u[2]; short4v s; } H, L;
    // result byte i <- sel: idx 0-3 = src1 bytes, idx 4-7 = src0 bytes
    H.u[0] = __builtin_amdgcn_perm(u1, u0, 0x07060302u);       // [u0.b2,u0.b3,u1.b2,u1.b3]
    H.u[1] = __builtin_amdgcn_perm(u3, u2, 0x07060302u);
    L.u[0] = __builtin_amdgcn_perm(fb(l1), fb(l0), 0x07060302u);
    L.u[1] = __builtin_amdgcn_perm(fb(l3), fb(l2), 0x07060302u);
    bfpair P; P.hi = H.s; P.lo = L.s; return P;
}

static __device__ __forceinline__ float sigmoid_f(float p) {
    return __builtin_amdgcn_rcpf(1.0f + __expf(-p));
}

__global__ __launch_bounds__(256, 8) void pcnet_kernel(
    const float* __restrict__ x,    // [B,16]
    const float* __restrict__ W1,   // [64,16]
    const float* __restrict__ b1,   // [64]
    const float* __restrict__ W2,   // [16,64]
    const float* __restrict__ b2,   // [16]
    const float* __restrict__ x1i,  // [B,64]
    const float* __restrict__ x2i,  // [B,16]
    float* __restrict__ out)        // [B,64] x1 then [B,16] x2
{
    const int tid  = blockIdx.x * 256 + threadIdx.x;
    const int wave = tid >> 6;
    const int lane = threadIdx.x & 63;
    const int g = lane >> 4;          // lane group 0..3
    const int q = lane & 15;          // 16x16 row/col index
    const int r = wave * 16 + q;      // batch row handled by this lane

    // ---- static split fragments ----
    // GEMM1 A-operand: W2 chunk c, elem j = W2[q][16c+4g+j]
    bfpair a_w2[4];
#pragma unroll
    for (int c = 0; c < 4; ++c) {
        float4v w = *(const float4v*)(W2 + q * 64 + 16 * c + 4 * g);
        a_w2[c] = split4(w);
    }
    // GEMM2 A-operand: tile t, elem j = 0.2 * W2[4g+j][16t+q]   (W2^T, pre-scaled)
    bfpair a_w2t[4];
#pragma unroll
    for (int t = 0; t < 4; ++t) {
        float4v e;
        e[0] = 0.2f * W2[(4 * g + 0) * 64 + 16 * t + q];
        e[1] = 0.2f * W2[(4 * g + 1) * 64 + 16 * t + q];
        e[2] = 0.2f * W2[(4 * g + 2) * 64 + 16 * t + q];
        e[3] = 0.2f * W2[(4 * g + 3) * 64 + 16 * t + q];
        a_w2t[t] = split4(e);
    }
    // b2 in GEMM1 output layout: acc[reg] = b2[4g+reg]
    const float4v b2f = *(const float4v*)(b2 + 4 * g);

    // ---- mu1 = sigmoid(x @ W1^T + b1), kept pre-scaled by 0.2, in X1 layout ----
    float4v xv = *(const float4v*)(x + r * 16 + 4 * g);
    bfpair bx = split4(xv);
    float4v mu1s[4];
#pragma unroll
    for (int t = 0; t < 4; ++t) {
        float4v aw = *(const float4v*)(W1 + (16 * t + q) * 16 + 4 * g);
        bfpair a1 = split4(aw);
        float4v acc = *(const float4v*)(b1 + 16 * t + 4 * g);
        acc = MFMA16(a1.hi, bx.hi, acc, 0, 0, 0);
        acc = MFMA16(a1.hi, bx.lo, acc, 0, 0, 0);
        acc = MFMA16(a1.lo, bx.hi, acc, 0, 0, 0);
#pragma unroll
        for (int j = 0; j < 4; ++j)
            mu1s[t][j] = 0.2f * sigmoid_f(acc[j]);
    }

    // ---- state (fp32 masters) ----
    float4v x1v[4];
#pragma unroll
    for (int t = 0; t < 4; ++t)
        x1v[t] = *(const float4v*)(x1i + r * 64 + 16 * t + 4 * g);
    float4v x2v = *(const float4v*)(x2i + r * 16 + 4 * g);

    // ---- 30 inference steps, zero memory traffic, zero cross-lane traffic ----
#pragma unroll 1
    for (int s = 0; s < NSTEPS; ++s) {
        // split X1 -> hi/lo bf16 B-fragments
        bfpair bx1[4];
#pragma unroll
        for (int c = 0; c < 4; ++c)
            bx1[c] = split4(x1v[c]);

        // GEMM1: mu2pre^T = W2 @ X1^T + b2 (acc init); hh + hl + lh products
        float4v p = b2f;
#pragma unroll
        for (int c = 0; c < 4; ++c)
            p = MFMA16(a_w2[c].hi, bx1[c].hi, p, 0, 0, 0);
#pragma unroll
        for (int c = 0; c < 4; ++c)
            p = MFMA16(a_w2[c].hi, bx1[c].lo, p, 0, 0, 0);
#pragma unroll
        for (int c = 0; c < 4; ++c)
            p = MFMA16(a_w2[c].lo, bx1[c].hi, p, 0, 0, 0);

        // sigmoid, d = e2*mu2*(1-mu2), x2 update  (all lane-local)
        float4v dv;
#pragma unroll
        for (int j = 0; j < 4; ++j) {
            float mu2 = sigmoid_f(p[j]);
            float e2  = x2v[j] - mu2;
            float mm  = mu2 - mu2 * mu2;               // mu2*(1-mu2)
            dv[j] = e2 * mm;
            x2v[j] = x2v[j] + 0.2f * (mu2 - x2v[j]);   // x2 <- 0.8 x2 + 0.2 mu2
        }
        bfpair bd = split4(dv);

        // GEMM2: x1' = [0.8*x1 + 0.2*mu1] (acc init) + 0.2*(W2^T @ D)
#pragma unroll
        for (int t = 0; t < 4; ++t) {
            float4v rg;
#pragma unroll
            for (int j = 0; j < 4; ++j)
                rg[j] = fmaf(0.8f, x1v[t][j], mu1s[t][j]);
            rg = MFMA16(a_w2t[t].hi, bd.hi, rg, 0, 0, 0);
            rg = MFMA16(a_w2t[t].hi, bd.lo, rg, 0, 0, 0);
            rg = MFMA16(a_w2t[t].lo, bd.hi, rg, 0, 0, 0);
            x1v[t] = rg;
        }
    }

    // ---- store results ----
#pragma unroll
    for (int t = 0; t < 4; ++t)
        *(float4v*)(out + r * 64 + 16 * t + 4 * g) = x1v[t];
    *(float4v*)(out + (size_t)NB * 64 + r * 16 + 4 * g) = x2v;
}

extern "C" void kernel_launch(void* const* d_in, const int* in_sizes, int n_in,
                              void* d_out, int out_size, void* d_ws, size_t ws_size,
                              hipStream_t stream) {
    const float* x   = (const float*)d_in[0];
    const float* W1  = (const float*)d_in[1];
    const float* b1  = (const float*)d_in[2];
    const float* W2  = (const float*)d_in[3];
    const float* b2  = (const float*)d_in[4];
    const float* x1i = (const float*)d_in[5];
    const float* x2i = (const float*)d_in[6];
    float* out = (float*)d_out;

    dim3 grid(NB / 64);   // 16 rows per wave, 4 waves per block
    dim3 block(256);
    pcnet_kernel<<<grid, block, 0, stream>>>(x, W1, b1, W2, b2, x1i, x2i, out);
}

// Round 5
// 78.522 us; speedup vs baseline: 3.1859x; 3.1859x over previous
//
#include <hip/hip_runtime.h>
#include <math.h>

#define NB 131072
#define NSTEPS 30

typedef float  float4v __attribute__((ext_vector_type(4)));
typedef short  short4v __attribute__((ext_vector_type(4)));

#define MFMA16 __builtin_amdgcn_mfma_f32_16x16x16bf16_1k

static __device__ __forceinline__ unsigned fb(float f) {
    union { float f; unsigned u; } c; c.f = f; return c.u;
}
static __device__ __forceinline__ float fu(unsigned u) {
    union { unsigned u; float f; } c; c.u = u; return c.f;
}

struct bfpair { short4v hi, lo; };

// Truncation split, pure C++: hi = trunc_bf16(v); lo = trunc_bf16(v - hi).
// v = hi + lo + err, |err| <= 2^-16 |v|.  12 VALU per 4 values.
static __device__ __forceinline__ bfpair split4(float4v v) {
    unsigned u0 = fb(v[0]), u1 = fb(v[1]), u2 = fb(v[2]), u3 = fb(v[3]);
    float l0 = v[0] - fu(u0 & 0xffff0000u);
    float l1 = v[1] - fu(u1 & 0xffff0000u);
    float l2 = v[2] - fu(u2 & 0xffff0000u);
    float l3 = v[3] - fu(u3 & 0xffff0000u);
    union { unsigned u[2]; short4v s; } H, L;
    H.u[0] = __builtin_amdgcn_perm(u1, u0, 0x07060302u);       // [hi(v0) | hi(v1)]
    H.u[1] = __builtin_amdgcn_perm(u3, u2, 0x07060302u);
    L.u[0] = __builtin_amdgcn_perm(fb(l1), fb(l0), 0x07060302u);
    L.u[1] = __builtin_amdgcn_perm(fb(l3), fb(l2), 0x07060302u);
    bfpair P; P.hi = H.s; P.lo = L.s; return P;
}

// hi-only truncation pack: 2 VALU per 4 values
static __device__ __forceinline__ short4v pack_hi4(float4v v) {
    union { unsigned u[2]; short4v s; } H;
    H.u[0] = __builtin_amdgcn_perm(fb(v[1]), fb(v[0]), 0x07060302u);
    H.u[1] = __builtin_amdgcn_perm(fb(v[3]), fb(v[2]), 0x07060302u);
    return H.s;
}

static __device__ __forceinline__ float sigmoid_f(float p) {
    return __builtin_amdgcn_rcpf(1.0f + __expf(-p));
}

__global__ __launch_bounds__(256, 3) void pcnet_kernel(
    const float* __restrict__ x,    // [B,16]
    const float* __restrict__ W1,   // [64,16]
    const float* __restrict__ b1,   // [64]
    const float* __restrict__ W2,   // [16,64]
    const float* __restrict__ b2,   // [16]
    const float* __restrict__ x1i,  // [B,64]
    const float* __restrict__ x2i,  // [B,16]
    float* __restrict__ out)        // [B,64] x1 then [B,16] x2
{
    const int tid  = blockIdx.x * 256 + threadIdx.x;
    const int wave = tid >> 6;
    const int lane = threadIdx.x & 63;
    const int g = lane >> 4;          // lane group 0..3
    const int q = lane & 15;          // 16x16 row/col index
    // two independent row groups per wave (ILP=2)
    int rr[2];
    rr[0] = wave * 32 + q;
    rr[1] = rr[0] + 16;

    // ---- static fragments (shared by both groups) ----
    // GEMM1 A-operand: W2 chunk c, elem j = W2[q][16c+4g+j], split hi/lo
    bfpair a_w2[4];
#pragma unroll
    for (int c = 0; c < 4; ++c) {
        float4v w = *(const float4v*)(W2 + q * 64 + 16 * c + 4 * g);
        a_w2[c] = split4(w);
    }
    // GEMM2 A-operand (hi only): tile t, elem j = 0.2 * W2[4g+j][16t+q]
    short4v a_w2t[4];
#pragma unroll
    for (int t = 0; t < 4; ++t) {
        float4v e;
        e[0] = 0.2f * W2[(4 * g + 0) * 64 + 16 * t + q];
        e[1] = 0.2f * W2[(4 * g + 1) * 64 + 16 * t + q];
        e[2] = 0.2f * W2[(4 * g + 2) * 64 + 16 * t + q];
        e[3] = 0.2f * W2[(4 * g + 3) * 64 + 16 * t + q];
        a_w2t[t] = pack_hi4(e);
    }
    const float4v b2f = *(const float4v*)(b2 + 4 * g);
    const float4v zero4 = {0.f, 0.f, 0.f, 0.f};

    // ---- mu1 = sigmoid(x @ W1^T + b1), pre-scaled by 0.2, X1 layout ----
    bfpair bx[2];
#pragma unroll
    for (int i = 0; i < 2; ++i)
        bx[i] = split4(*(const float4v*)(x + rr[i] * 16 + 4 * g));
    float4v mu1s[2][4];
#pragma unroll
    for (int t = 0; t < 4; ++t) {
        float4v aw = *(const float4v*)(W1 + (16 * t + q) * 16 + 4 * g);
        bfpair a1 = split4(aw);                       // shared across groups
        float4v binit = *(const float4v*)(b1 + 16 * t + 4 * g);
#pragma unroll
        for (int i = 0; i < 2; ++i) {
            float4v acc = binit;
            acc = MFMA16(a1.hi, bx[i].hi, acc, 0, 0, 0);
            acc = MFMA16(a1.hi, bx[i].lo, acc, 0, 0, 0);
            acc = MFMA16(a1.lo, bx[i].hi, acc, 0, 0, 0);
#pragma unroll
            for (int j = 0; j < 4; ++j)
                mu1s[i][t][j] = 0.2f * sigmoid_f(acc[j]);
        }
    }

    // ---- state (fp32 masters) ----
    float4v x1v[2][4];
    float4v x2v[2];
#pragma unroll
    for (int i = 0; i < 2; ++i) {
#pragma unroll
        for (int t = 0; t < 4; ++t)
            x1v[i][t] = *(const float4v*)(x1i + rr[i] * 64 + 16 * t + 4 * g);
        x2v[i] = *(const float4v*)(x2i + rr[i] * 16 + 4 * g);
    }

    // ---- 30 inference steps ----
#pragma unroll 1
    for (int s = 0; s < NSTEPS; ++s) {
        // GEMM1: 3 independent acc chains per group (hh, hl, lh), depth 4
        float4v pa[2], pb[2], pc[2];
#pragma unroll
        for (int i = 0; i < 2; ++i) { pa[i] = b2f; pb[i] = zero4; pc[i] = zero4; }
#pragma unroll
        for (int c = 0; c < 4; ++c) {
#pragma unroll
            for (int i = 0; i < 2; ++i) {
                bfpair bx1 = split4(x1v[i][c]);        // split on demand
                pa[i] = MFMA16(a_w2[c].hi, bx1.hi, pa[i], 0, 0, 0);
                pb[i] = MFMA16(a_w2[c].hi, bx1.lo, pb[i], 0, 0, 0);
                pc[i] = MFMA16(a_w2[c].lo, bx1.hi, pc[i], 0, 0, 0);
            }
        }

        // sigmoid, d = e2*mu2*(1-mu2), x2 update; pack d (hi only)
        short4v bd[2];
#pragma unroll
        for (int i = 0; i < 2; ++i) {
            float4v p = (pa[i] + pb[i]) + pc[i];
            float4v dv;
#pragma unroll
            for (int j = 0; j < 4; ++j) {
                float mu2 = sigmoid_f(p[j]);
                float e2  = x2v[i][j] - mu2;
                float mm  = mu2 - mu2 * mu2;
                dv[j] = e2 * mm;
                x2v[i][j] = x2v[i][j] + 0.2f * (mu2 - x2v[i][j]);
            }
            bd[i] = pack_hi4(dv);
        }

        // GEMM2 (single product): x1' = [0.8*x1 + 0.2*mu1](init) + 0.2*(W2^T @ D)
#pragma unroll
        for (int i = 0; i < 2; ++i) {
#pragma unroll
            for (int t = 0; t < 4; ++t) {
                float4v rg;
#pragma unroll
                for (int j = 0; j < 4; ++j)
                    rg[j] = fmaf(0.8f, x1v[i][t][j], mu1s[i][t][j]);
                rg = MFMA16(a_w2t[t], bd[i], rg, 0, 0, 0);
                x1v[i][t] = rg;
            }
        }
    }

    // ---- store results ----
#pragma unroll
    for (int i = 0; i < 2; ++i) {
#pragma unroll
        for (int t = 0; t < 4; ++t)
            *(float4v*)(out + rr[i] * 64 + 16 * t + 4 * g) = x1v[i][t];
        *(float4v*)(out + (size_t)NB * 64 + rr[i] * 16 + 4 * g) = x2v[i];
    }
}

extern "C" void kernel_launch(void* const* d_in, const int* in_sizes, int n_in,
                              void* d_out, int out_size, void* d_ws, size_t ws_size,
                              hipStream_t stream) {
    const float* x   = (const float*)d_in[0];
    const float* W1  = (const float*)d_in[1];
    const float* b1  = (const float*)d_in[2];
    const float* W2  = (const float*)d_in[3];
    const float* b2  = (const float*)d_in[4];
    const float* x1i = (const float*)d_in[5];
    const float* x2i = (const float*)d_in[6];
    float* out = (float*)d_out;

    dim3 grid(NB / 128);   // 32 rows per wave, 4 waves per block
    dim3 block(256);
    pcnet_kernel<<<grid, block, 0, stream>>>(x, W1, b1, W2, b2, x1i, x2i, out);
}

// Round 6
// 36.364 us; speedup vs baseline: 6.8795x; 2.1593x over previous
//
#include <hip/hip_runtime.h>
#include <math.h>

#define NB 131072
#define NSTEPS 30
// 0.8^30 and 1-0.8^30
#define LAMBDA  1.2379400392853803e-3f
#define ONEMLAM 0.9987620599607146f

typedef float  float4v __attribute__((ext_vector_type(4)));
typedef short  short4v __attribute__((ext_vector_type(4)));

#define MFMA16 __builtin_amdgcn_mfma_f32_16x16x16bf16_1k

static __device__ __forceinline__ unsigned fb(float f) {
    union { float f; unsigned u; } c; c.f = f; return c.u;
}
static __device__ __forceinline__ float fu(unsigned u) {
    union { unsigned u; float f; } c; c.u = u; return c.f;
}

struct bfpair { short4v hi, lo; };

// Truncation split, pure C++: hi = trunc_bf16(v); lo = trunc_bf16(v - hi).
// v = hi + lo + err, |err| <= 2^-16 |v|.
static __device__ __forceinline__ bfpair split4(float4v v) {
    unsigned u0 = fb(v[0]), u1 = fb(v[1]), u2 = fb(v[2]), u3 = fb(v[3]);
    float l0 = v[0] - fu(u0 & 0xffff0000u);
    float l1 = v[1] - fu(u1 & 0xffff0000u);
    float l2 = v[2] - fu(u2 & 0xffff0000u);
    float l3 = v[3] - fu(u3 & 0xffff0000u);
    union { unsigned u[2]; short4v s; } H, L;
    H.u[0] = __builtin_amdgcn_perm(u1, u0, 0x07060302u);       // [hi(v0) | hi(v1)]
    H.u[1] = __builtin_amdgcn_perm(u3, u2, 0x07060302u);
    L.u[0] = __builtin_amdgcn_perm(fb(l1), fb(l0), 0x07060302u);
    L.u[1] = __builtin_amdgcn_perm(fb(l3), fb(l2), 0x07060302u);
    bfpair P; P.hi = H.s; P.lo = L.s; return P;
}

// hi-only truncation pack: 2 VALU per 4 values
static __device__ __forceinline__ short4v pack_hi4(float4v v) {
    union { unsigned u[2]; short4v s; } H;
    H.u[0] = __builtin_amdgcn_perm(fb(v[1]), fb(v[0]), 0x07060302u);
    H.u[1] = __builtin_amdgcn_perm(fb(v[3]), fb(v[2]), 0x07060302u);
    return H.s;
}

static __device__ __forceinline__ float sigmoid_f(float p) {
    return __builtin_amdgcn_rcpf(1.0f + __expf(-p));
}

__global__ __launch_bounds__(256, 6) void pcnet_kernel(
    const float* __restrict__ x,    // [B,16]
    const float* __restrict__ W1,   // [64,16]
    const float* __restrict__ b1,   // [64]
    const float* __restrict__ W2,   // [16,64]
    const float* __restrict__ b2,   // [16]
    const float* __restrict__ x1i,  // [B,64]
    const float* __restrict__ x2i,  // [B,16]
    float* __restrict__ out)        // [B,64] x1 then [B,16] x2
{
    const int tid  = blockIdx.x * 256 + threadIdx.x;
    const int wave = tid >> 6;
    const int lane = threadIdx.x & 63;
    const int g = lane >> 4;          // lane group 0..3
    const int q = lane & 15;          // 16x16 row/col index
    const int r = wave * 16 + q;      // batch row handled by this lane

    // ---- W2 split fragments (A-operand: A[q][4g+j] = W2[q][16c+4g+j]) ----
    bfpair a_w2[4];
#pragma unroll
    for (int c = 0; c < 4; ++c) {
        float4v w = *(const float4v*)(W2 + q * 64 + 16 * c + 4 * g);
        a_w2[c] = split4(w);
    }
    const float4v b2f = *(const float4v*)(b2 + 4 * g);   // b2[4g+j] (C-row layout)
    const float4v zero4 = {0.f, 0.f, 0.f, 0.f};

    // ---- mu1 = sigmoid(x @ W1^T + b1), C-layout chunks ----
    float4v xv = *(const float4v*)(x + r * 16 + 4 * g);
    bfpair bx = split4(xv);
    float4v mu1v[4];
#pragma unroll
    for (int t = 0; t < 4; ++t) {
        float4v aw = *(const float4v*)(W1 + (16 * t + q) * 16 + 4 * g);
        bfpair a1 = split4(aw);
        float4v acc = *(const float4v*)(b1 + 16 * t + 4 * g);
        acc = MFMA16(a1.hi, bx.hi, acc, 0, 0, 0);
        acc = MFMA16(a1.hi, bx.lo, acc, 0, 0, 0);
        acc = MFMA16(a1.lo, bx.hi, acc, 0, 0, 0);
#pragma unroll
        for (int j = 0; j < 4; ++j)
            mu1v[t][j] = sigmoid_f(acc[j]);
    }

    // ---- c1 = W2 @ mu1 (per row), then q = 0.2*(b2 + c1) ----
    float4v c1 = zero4;
#pragma unroll
    for (int c = 0; c < 4; ++c) {
        bfpair bm = split4(mu1v[c]);
        c1 = MFMA16(a_w2[c].hi, bm.hi, c1, 0, 0, 0);
        c1 = MFMA16(a_w2[c].hi, bm.lo, c1, 0, 0, 0);
        c1 = MFMA16(a_w2[c].lo, bm.hi, c1, 0, 0, 0);
    }
    float4v qv;
#pragma unroll
    for (int j = 0; j < 4; ++j) qv[j] = 0.2f * (b2f[j] + c1[j]);

    // ---- p0 = W2 @ x1_0 + b2; keep lambda*x1_0 for epilogue ----
    float4v x1l[4];
#pragma unroll
    for (int t = 0; t < 4; ++t)
        x1l[t] = *(const float4v*)(x1i + r * 64 + 16 * t + 4 * g);
    float4v pv = b2f;
#pragma unroll
    for (int c = 0; c < 4; ++c) {
        bfpair b1s = split4(x1l[c]);
        pv = MFMA16(a_w2[c].hi, b1s.hi, pv, 0, 0, 0);
        pv = MFMA16(a_w2[c].hi, b1s.lo, pv, 0, 0, 0);
        pv = MFMA16(a_w2[c].lo, b1s.hi, pv, 0, 0, 0);
    }
#pragma unroll
    for (int t = 0; t < 4; ++t) x1l[t] *= LAMBDA;

    // ---- M_hat = 0.2 * (W2 @ W2^T) — 16x16, symmetric, so C-layout == A-frag ----
    float4v Mv = zero4;
#pragma unroll
    for (int c = 0; c < 4; ++c) {
        Mv = MFMA16(a_w2[c].hi, a_w2[c].hi, Mv, 0, 0, 0);
        Mv = MFMA16(a_w2[c].hi, a_w2[c].lo, Mv, 0, 0, 0);
        Mv = MFMA16(a_w2[c].lo, a_w2[c].hi, Mv, 0, 0, 0);
    }
    bfpair mfr = split4(0.2f * Mv);

    // ---- scale mu1 -> (1-lambda)*mu1 for epilogue ----
#pragma unroll
    for (int t = 0; t < 4; ++t) mu1v[t] *= ONEMLAM;

    // ---- state: p (16-dim proj), x2, S = sum 0.8^k d ----
    float4v x2v = *(const float4v*)(x2i + r * 16 + 4 * g);
    float4v Sv = zero4;

    // ---- 30 steps, entirely in 16-dim space: ~30 VALU + 8 trans + 2 MFMA ----
#pragma unroll 1
    for (int s = 0; s < NSTEPS; ++s) {
        float4v dv;
#pragma unroll
        for (int j = 0; j < 4; ++j) {
            float mu2 = sigmoid_f(pv[j]);
            float e2  = x2v[j] - mu2;
            float mm  = fmaf(-mu2, mu2, mu2);          // mu2*(1-mu2)
            dv[j]  = e2 * mm;
            x2v[j] = fmaf(-0.2f, e2, x2v[j]);          // x2' = x2 - 0.2 e2
            Sv[j]  = fmaf(0.8f, Sv[j], dv[j]);         // S' = 0.8 S + d
        }
        short4v bd = pack_hi4(dv);
        float4v pn;
#pragma unroll
        for (int j = 0; j < 4; ++j) pn[j] = fmaf(0.8f, pv[j], qv[j]);
        pn = MFMA16(mfr.hi, bd, pn, 0, 0, 0);
        pn = MFMA16(mfr.lo, bd, pn, 0, 0, 0);
        pv = pn;
    }

    // ---- epilogue: x1_N = lambda*x1_0 + (1-lambda)*mu1 + 0.2*W2^T @ S ----
    // A-frag per t: A_t[q][4g+j] = 0.2*W2[4g+j][16t+q]  (gathered now, L2-hot)
    short4v bs = pack_hi4(Sv);
#pragma unroll
    for (int t = 0; t < 4; ++t) {
        float4v e;
        e[0] = 0.2f * W2[(4 * g + 0) * 64 + 16 * t + q];
        e[1] = 0.2f * W2[(4 * g + 1) * 64 + 16 * t + q];
        e[2] = 0.2f * W2[(4 * g + 2) * 64 + 16 * t + q];
        e[3] = 0.2f * W2[(4 * g + 3) * 64 + 16 * t + q];
        bfpair a_ep = split4(e);
        float4v acc = x1l[t] + mu1v[t];
        acc = MFMA16(a_ep.hi, bs, acc, 0, 0, 0);
        acc = MFMA16(a_ep.lo, bs, acc, 0, 0, 0);
        *(float4v*)(out + r * 64 + 16 * t + 4 * g) = acc;
    }
    *(float4v*)(out + (size_t)NB * 64 + r * 16 + 4 * g) = x2v;
}

extern "C" void kernel_launch(void* const* d_in, const int* in_sizes, int n_in,
                              void* d_out, int out_size, void* d_ws, size_t ws_size,
                              hipStream_t stream) {
    const float* x   = (const float*)d_in[0];
    const float* W1  = (const float*)d_in[1];
    const float* b1  = (const float*)d_in[2];
    const float* W2  = (const float*)d_in[3];
    const float* b2  = (const float*)d_in[4];
    const float* x1i = (const float*)d_in[5];
    const float* x2i = (const float*)d_in[6];
    float* out = (float*)d_out;

    dim3 grid(NB / 64);   // 16 rows per wave, 4 waves per block
    dim3 block(256);
    pcnet_kernel<<<grid, block, 0, stream>>>(x, W1, b1, W2, b2, x1i, x2i, out);
}